// Round 9
// baseline (541.835 us; speedup 1.0000x reference)
//
#include <hip/hip_runtime.h>

typedef __bf16 bf16;
typedef __bf16 bf16x4 __attribute__((ext_vector_type(4)));
typedef __bf16 bf16x8 __attribute__((ext_vector_type(8)));
typedef float  floatx4 __attribute__((ext_vector_type(4)));

#define L_SEQ   2048
#define C_SEQ   256
#define S_SEQ   2304
#define NBATCH  4
#define NHEAD   16
#define DHEAD   64
#define DMODEL  1024
#define RMS_EPS 1.1920928955078125e-07f
#define LIN_EPS 1e-6f

// ---------------------------------------------------------------- transpose
// src: R x C f32 -> dst: C x R bf16 (fused convert)
__global__ __launch_bounds__(256) void transpose_f32_bf16(
    const float* __restrict__ src, bf16* __restrict__ dst, int R, int C) {
  __shared__ bf16 tile[32][33];
  int c0 = blockIdx.x * 32, r0 = blockIdx.y * 32;
  int tx = threadIdx.x & 31, ty = threadIdx.x >> 5;
  for (int i = ty; i < 32; i += 8)
    tile[i][tx] = (bf16)src[(size_t)(r0 + i) * C + c0 + tx];
  __syncthreads();
  for (int i = ty; i < 32; i += 8)
    dst[(size_t)(c0 + i) * R + r0 + tx] = tile[tx][i];
}

// ---------------------------------------------------------------- GEMM
// C = A[M][K] @ Bt[N][K]^T + bias[N]; A f32 or bf16; fp32 accum; bf16 out.
// SCATTER=true: col -> (which={q,k,v}, h, dh), row -> (b, s) head-major slabs.
// 128x128 tile, BK=32, 4 waves, 4x4 mfma_16x16x32_bf16 per wave.
template <typename TA, bool SCATTER>
__global__ __launch_bounds__(256) void gemm_bias(
    const TA* __restrict__ A, const bf16* __restrict__ Bt,
    const float* __restrict__ bias, bf16* __restrict__ C0,
    bf16* __restrict__ qs, bf16* __restrict__ ks, bf16* __restrict__ vs,
    int M, int N, int K, int rpb_shift, int seq_off) {
  constexpr bool A_F32 = (sizeof(TA) == 4);
  __shared__ bf16 As[128][40];   // 80 B rows: 20-bank stride, 2-way (free)
  __shared__ bf16 Bs[128][40];
  int n0 = blockIdx.x * 128, m0 = blockIdx.y * 128;
  int t = threadIdx.x;
  int lane = t & 63, w = t >> 6;
  int wm = (w & 1) * 64, wn = (w >> 1) * 64;
  int row = t >> 1, kseg = (t & 1) * 16;
  int l16 = lane & 15, l4 = lane >> 4;

  floatx4 acc[4][4] = {};
  for (int kb = 0; kb < K; kb += 32) {
    bf16x8 av0, av1, bv0, bv1;
    const bf16* bg = Bt + (size_t)(n0 + row) * K + kb + kseg;
    bv0 = *(const bf16x8*)bg;
    bv1 = *(const bf16x8*)(bg + 8);
    if constexpr (A_F32) {
      const float* ag = (const float*)A + (size_t)(m0 + row) * K + kb + kseg;
      floatx4 a0 = *(const floatx4*)ag;
      floatx4 a1 = *(const floatx4*)(ag + 4);
      floatx4 a2 = *(const floatx4*)(ag + 8);
      floatx4 a3 = *(const floatx4*)(ag + 12);
#pragma unroll
      for (int i = 0; i < 4; i++) {
        av0[i]     = (bf16)a0[i];
        av0[4 + i] = (bf16)a1[i];
        av1[i]     = (bf16)a2[i];
        av1[4 + i] = (bf16)a3[i];
      }
    } else {
      const bf16* ag = (const bf16*)A + (size_t)(m0 + row) * K + kb + kseg;
      av0 = *(const bf16x8*)ag;
      av1 = *(const bf16x8*)(ag + 8);
    }
    __syncthreads();                 // protect prior iter's LDS reads
    *(bf16x8*)&As[row][kseg]     = av0;
    *(bf16x8*)&As[row][kseg + 8] = av1;
    *(bf16x8*)&Bs[row][kseg]     = bv0;
    *(bf16x8*)&Bs[row][kseg + 8] = bv1;
    __syncthreads();
    bf16x8 af[4], bfr[4];
#pragma unroll
    for (int i = 0; i < 4; i++) {
      af[i]  = *(const bf16x8*)&As[wm + i * 16 + l16][l4 * 8];
      bfr[i] = *(const bf16x8*)&Bs[wn + i * 16 + l16][l4 * 8];
    }
#pragma unroll
    for (int i = 0; i < 4; i++)
#pragma unroll
      for (int j = 0; j < 4; j++)
        acc[i][j] = __builtin_amdgcn_mfma_f32_16x16x32_bf16(af[i], bfr[j], acc[i][j], 0, 0, 0);
  }
  // epilogue: D[row=(l>>4)*4+r][col=l&15] per 16x16 tile
#pragma unroll
  for (int i = 0; i < 4; i++)
#pragma unroll
    for (int j = 0; j < 4; j++) {
      int col = n0 + wn + j * 16 + l16;
      float bval = bias[col];
      if constexpr (SCATTER) {
        int which = col >> 10;
        int h = (col >> 6) & 15;
        int dh = col & 63;
        bf16* dst = which == 0 ? qs : (which == 1 ? ks : vs);
        int rmask = (1 << rpb_shift) - 1;
#pragma unroll
        for (int r = 0; r < 4; r++) {
          int rw = m0 + wm + i * 16 + l4 * 4 + r;
          int b = rw >> rpb_shift;
          int s = seq_off + (rw & rmask);
          dst[((size_t)(b * NHEAD + h) * S_SEQ + s) * DHEAD + dh] =
              (bf16)(acc[i][j][r] + bval);
        }
      } else {
#pragma unroll
        for (int r = 0; r < 4; r++) {
          int rw = m0 + wm + i * 16 + l4 * 4 + r;
          C0[(size_t)rw * N + col] = (bf16)(acc[i][j][r] + bval);
        }
      }
    }
}

// ---------------------------------------------------------------- anymask
__global__ __launch_bounds__(256) void anymask_kernel(
    const int* __restrict__ mask, int* __restrict__ anym) {
  int b = blockIdx.x, t = threadIdx.x;
  int a = 0;
  size_t base = (size_t)b * L_SEQ * L_SEQ;      // row 0 of batch b
  for (int j = t; j < L_SEQ; j += 256) a |= mask[base + j];
  __shared__ int sh;
  if (t == 0) sh = 0;
  __syncthreads();
  if (a) atomicOr(&sh, 1);
  __syncthreads();
  if (t == 0) anym[b] = sh;
}

__global__ __launch_bounds__(256) void zero_f32(float* __restrict__ p, int n) {
  for (int i = blockIdx.x * 256 + threadIdx.x; i < n; i += gridDim.x * 256)
    p[i] = 0.f;
}

// ---------------------------------------------------------------- qkv post
// One block per token (9216). In-place on head-major q/k slabs: rmsnorm over
// D=1024, RoPE (x tokens only), relu; key-mask on k.
__global__ __launch_bounds__(256) void qkv_post(
    bf16* __restrict__ qs, bf16* __restrict__ ks,
    const int* __restrict__ mask, const int* __restrict__ spos,
    const int* __restrict__ anym,
    const float* __restrict__ g_q, const float* __restrict__ g_k,
    const float* __restrict__ cg_q, const float* __restrict__ cg_k) {
  int g = blockIdx.x, t = threadIdx.x;
  bool is_ctx = g >= NBATCH * L_SEQ;
  int b, s;
  const float *gq, *gk;
  float mval;
  if (!is_ctx) {
    b = g >> 11;
    int l = g & 2047;
    s = l;
    mval = mask[(size_t)b * L_SEQ * L_SEQ + l] ? 1.f : 0.f;  // mask[b][0][l]
    gq = g_q; gk = g_k;
  } else {
    int gg = g - NBATCH * L_SEQ;
    b = gg >> 8;
    s = L_SEQ + (gg & 255);
    mval = anym[b] ? 1.f : 0.f;
    gq = cg_q; gk = cg_k;
  }
  int d0 = t * 4;
  int h = t >> 4, dh = (t & 15) * 4;            // h*64+dh == d0
  size_t base = ((size_t)(b * NHEAD + h) * S_SEQ + s) * DHEAD + dh;
  bf16x4 q4 = *(const bf16x4*)(qs + base);
  bf16x4 k4 = *(const bf16x4*)(ks + base);
  float qv[4], kv[4], pq = 0.f, pk = 0.f;
#pragma unroll
  for (int i = 0; i < 4; i++) {
    qv[i] = (float)q4[i]; kv[i] = (float)k4[i];
    pq += qv[i] * qv[i];  pk += kv[i] * kv[i];
  }
  int lane = t & 63, w = t >> 6;
  for (int off = 32; off > 0; off >>= 1) {
    pq += __shfl_down(pq, off, 64);
    pk += __shfl_down(pk, off, 64);
  }
  __shared__ float red[8];
  if (lane == 0) { red[w] = pq; red[4 + w] = pk; }
  __syncthreads();
  float sq = red[0] + red[1] + red[2] + red[3];
  float sk = red[4] + red[5] + red[6] + red[7];
  float scq = rsqrtf(sq * (1.f / DMODEL) + RMS_EPS);
  float sck = rsqrtf(sk * (1.f / DMODEL) + RMS_EPS);
#pragma unroll
  for (int i = 0; i < 4; i++) {
    qv[i] *= scq * gq[d0 + i];
    kv[i] *= sck * gk[d0 + i];
  }
  if (!is_ctx) {
    float p = (float)(spos[b] + s);
#pragma unroll
    for (int pr = 0; pr < 2; pr++) {
      int fi = (dh >> 1) + pr;                              // freq 0..31
      float ang = p * expf((float)fi * -0.28782313662425572f);  // ln(1e4)/32
      float cc = cosf(ang), ss = sinf(ang);
      float t0 = qv[2 * pr], t1 = qv[2 * pr + 1];
      qv[2 * pr]     = t0 * cc - t1 * ss;
      qv[2 * pr + 1] = t0 * ss + t1 * cc;
      t0 = kv[2 * pr]; t1 = kv[2 * pr + 1];
      kv[2 * pr]     = t0 * cc - t1 * ss;
      kv[2 * pr + 1] = t0 * ss + t1 * cc;
    }
  }
  bf16x4 qo, ko;
#pragma unroll
  for (int i = 0; i < 4; i++) {
    qo[i] = (bf16)fmaxf(qv[i], 0.f);
    ko[i] = (bf16)(fmaxf(kv[i], 0.f) * mval);
  }
  *(bf16x4*)(qs + base) = qo;
  *(bf16x4*)(ks + base) = ko;
}

// ---------------------------------------------------------------- vk accum
// vk[bh][e][d] = sum_s vpad[s][e]*kf[s][d]; e=64 row = sum_s kf[s][d].
__global__ __launch_bounds__(256) void vk_accum(
    const bf16* __restrict__ kf, const bf16* __restrict__ v,
    float* __restrict__ vk) {
  int bh = blockIdx.x >> 2, chunk = blockIdx.x & 3;
  int t = threadIdx.x;
  int d = t & 63, eg = t >> 6, e0 = eg * 16;
  const bf16* kfp = kf + (size_t)bh * S_SEQ * DHEAD;
  const bf16* vp  = v  + (size_t)bh * S_SEQ * DHEAD;
  float acc[16] = {};
  float dacc = 0.f;
  int s0 = chunk * 576, s1 = s0 + 576;
  for (int s = s0; s < s1; s++) {
    float kval = (float)kfp[(size_t)s * DHEAD + d];
    bf16x8 va = *(const bf16x8*)(vp + (size_t)s * DHEAD + e0);
    bf16x8 vb = *(const bf16x8*)(vp + (size_t)s * DHEAD + e0 + 8);
#pragma unroll
    for (int i = 0; i < 8; i++) acc[i] += (float)va[i] * kval;
#pragma unroll
    for (int i = 0; i < 8; i++) acc[8 + i] += (float)vb[i] * kval;
    dacc += kval;
  }
  float* vkbh = vk + (size_t)bh * 65 * 64;
#pragma unroll
  for (int i = 0; i < 16; i++) atomicAdd(&vkbh[(e0 + i) * 64 + d], acc[i]);
  if (eg == 0) atomicAdd(&vkbh[64 * 64 + d], dacc);
}

// ---------------------------------------------------------------- res + div
// res[q][e] = sum_d qf[q][d]*vk[e][d]; attn = res[:,:64]/(res[:,64]+eps).
__global__ __launch_bounds__(256) void res_attn(
    const bf16* __restrict__ qf, const float* __restrict__ vk,
    bf16* __restrict__ attn_x, bf16* __restrict__ attn_c) {
  __shared__ bf16 Bs[80][72];
  __shared__ float sden[256];
  int bh = blockIdx.x / 9, mblk = blockIdx.x % 9;
  int b = bh >> 4, h = bh & 15;
  int t = threadIdx.x, lane = t & 63, w = t >> 6;
  const float* vkp = vk + (size_t)bh * 65 * 64;
  for (int i = t; i < 80 * 64; i += 256) {
    int e = i >> 6, d = i & 63;
    Bs[e][d] = (bf16)(e < 65 ? vkp[i] : 0.f);
  }
  __syncthreads();
  int l16 = lane & 15, l4 = lane >> 4;
  const bf16* qbase = qf + (size_t)bh * S_SEQ * DHEAD;
  int q0w = mblk * 256 + w * 64;

  floatx4 acc[4][5] = {};
  bf16x8 af[4][2], bfr[5][2];
#pragma unroll
  for (int mt = 0; mt < 4; mt++) {
    int q = q0w + mt * 16 + l16;
    af[mt][0] = *(const bf16x8*)(qbase + (size_t)q * 64 + l4 * 8);
    af[mt][1] = *(const bf16x8*)(qbase + (size_t)q * 64 + 32 + l4 * 8);
  }
#pragma unroll
  for (int nt = 0; nt < 5; nt++) {
    bfr[nt][0] = *(const bf16x8*)&Bs[nt * 16 + l16][l4 * 8];
    bfr[nt][1] = *(const bf16x8*)&Bs[nt * 16 + l16][32 + l4 * 8];
  }
#pragma unroll
  for (int mt = 0; mt < 4; mt++)
#pragma unroll
    for (int nt = 0; nt < 5; nt++) {
      acc[mt][nt] = __builtin_amdgcn_mfma_f32_16x16x32_bf16(af[mt][0], bfr[nt][0], acc[mt][nt], 0, 0, 0);
      acc[mt][nt] = __builtin_amdgcn_mfma_f32_16x16x32_bf16(af[mt][1], bfr[nt][1], acc[mt][nt], 0, 0, 0);
    }
  // denominator: e=64 = col 0 of n-tile 4 (lanes with l16==0)
  if (l16 == 0) {
#pragma unroll
    for (int mt = 0; mt < 4; mt++)
#pragma unroll
      for (int r = 0; r < 4; r++)
        sden[w * 64 + mt * 16 + l4 * 4 + r] = acc[mt][4][r];
  }
  __syncthreads();
#pragma unroll
  for (int mt = 0; mt < 4; mt++)
#pragma unroll
    for (int r = 0; r < 4; r++) {
      float den = sden[w * 64 + mt * 16 + l4 * 4 + r] + LIN_EPS;
      float rden = 1.f / den;
      int q = q0w + mt * 16 + l4 * 4 + r;
#pragma unroll
      for (int nt = 0; nt < 4; nt++) {
        int dcol = nt * 16 + l16;
        float a = acc[mt][nt][r] * rden;
        if (q < L_SEQ)
          attn_x[((size_t)b * L_SEQ + q) * DMODEL + h * DHEAD + dcol] = (bf16)a;
        else
          attn_c[((size_t)b * C_SEQ + (q - L_SEQ)) * DMODEL + h * DHEAD + dcol] = (bf16)a;
      }
    }
}

// ---------------------------------------------------------------- final norm
// Reads bf16 y, writes FLOAT32 output (the reference's output dtype).
__global__ __launch_bounds__(256) void final_norm(
    const bf16* __restrict__ y_x, const bf16* __restrict__ y_c,
    const float* __restrict__ g_out, const float* __restrict__ cg_out,
    float* __restrict__ out) {
  int g = blockIdx.x, t = threadIdx.x;
  const bf16* src;
  const float* gv;
  if (g < NBATCH * L_SEQ) {
    src = y_x + (size_t)g * DMODEL; gv = g_out;
  } else {
    int gg = g - NBATCH * L_SEQ;
    src = y_c + (size_t)gg * DMODEL; gv = cg_out;
  }
  float* dst = out + (size_t)g * DMODEL;
  int d0 = t * 4;
  bf16x4 y4 = *(const bf16x4*)(src + d0);
  float yv[4], p = 0.f;
#pragma unroll
  for (int i = 0; i < 4; i++) { yv[i] = (float)y4[i]; p += yv[i] * yv[i]; }
  int lane = t & 63, w = t >> 6;
  for (int off = 32; off > 0; off >>= 1) p += __shfl_down(p, off, 64);
  __shared__ float red[4];
  if (lane == 0) red[w] = p;
  __syncthreads();
  float ssum = red[0] + red[1] + red[2] + red[3];
  float sc = rsqrtf(ssum * (1.f / DMODEL) + RMS_EPS);
  floatx4 o;
#pragma unroll
  for (int i = 0; i < 4; i++) o[i] = yv[i] * sc * gv[d0 + i];
  *(floatx4*)(dst + d0) = o;
}

// ---------------------------------------------------------------- launch
extern "C" void kernel_launch(void* const* d_in, const int* in_sizes, int n_in,
                              void* d_out, int out_size, void* d_ws, size_t ws_size,
                              hipStream_t stream) {
  const float* x      = (const float*)d_in[0];
  const float* ctx    = (const float*)d_in[1];
  const int*   mask   = (const int*)d_in[2];
  const int*   spos   = (const int*)d_in[3];
  const float* Wqkv   = (const float*)d_in[4];
  const float* bqkv   = (const float*)d_in[5];
  const float* g_q    = (const float*)d_in[6];
  const float* g_k    = (const float*)d_in[7];
  const float* cWqkv  = (const float*)d_in[8];
  const float* cbqkv  = (const float*)d_in[9];
  const float* cg_q   = (const float*)d_in[10];
  const float* cg_k   = (const float*)d_in[11];
  const float* Wout   = (const float*)d_in[12];
  const float* bout   = (const float*)d_in[13];
  const float* g_out  = (const float*)d_in[14];
  const float* cWout  = (const float*)d_in[15];
  const float* cbout  = (const float*)d_in[16];
  const float* cg_out = (const float*)d_in[17];

  char* wsp = (char*)d_ws;
  size_t off = 0;
  auto alloc = [&](size_t bytes) -> void* {
    void* p = wsp + off;
    off += (bytes + 255) & ~(size_t)255;
    return p;
  };
  bf16* WqkvT  = (bf16*)alloc((size_t)3072 * 1024 * 2);
  bf16* cWqkvT = (bf16*)alloc((size_t)3072 * 1024 * 2);
  bf16* WoutT  = (bf16*)alloc((size_t)1024 * 1024 * 2);
  bf16* cWoutT = (bf16*)alloc((size_t)1024 * 1024 * 2);
  const size_t SLAB = (size_t)NBATCH * NHEAD * S_SEQ * DHEAD;  // 9,437,184
  bf16* qfs    = (bf16*)alloc(SLAB * 2);
  bf16* kfs    = (bf16*)alloc(SLAB * 2);
  bf16* vfs    = (bf16*)alloc(SLAB * 2);
  float* vkw   = (float*)alloc((size_t)64 * 65 * 64 * 4);
  int* anym    = (int*)alloc(256);
  // attn aliases kf slab (dead after vk_accum); y aliases v slab.
  bf16* attn_x = kfs;
  bf16* attn_c = kfs + (size_t)NBATCH * L_SEQ * DMODEL;
  bf16* y_x    = vfs;
  bf16* y_c    = vfs + (size_t)NBATCH * L_SEQ * DMODEL;

  // 1) weight transposes+convert (N x K bf16 for MFMA B-operand)
  transpose_f32_bf16<<<dim3(96, 32), 256, 0, stream>>>(Wqkv, WqkvT, 1024, 3072);
  transpose_f32_bf16<<<dim3(96, 32), 256, 0, stream>>>(cWqkv, cWqkvT, 1024, 3072);
  transpose_f32_bf16<<<dim3(32, 32), 256, 0, stream>>>(Wout, WoutT, 1024, 1024);
  transpose_f32_bf16<<<dim3(32, 32), 256, 0, stream>>>(cWout, cWoutT, 1024, 1024);

  // 2) QKV projections -> head-major q/k/v slabs
  gemm_bias<float, true><<<dim3(24, 64), 256, 0, stream>>>(
      x, WqkvT, bqkv, nullptr, qfs, kfs, vfs, 8192, 3072, 1024, 11, 0);
  gemm_bias<float, true><<<dim3(24, 8), 256, 0, stream>>>(
      ctx, cWqkvT, cbqkv, nullptr, qfs, kfs, vfs, 1024, 3072, 1024, 8, L_SEQ);

  // 3) mask helper + zero vk accumulator
  anymask_kernel<<<4, 256, 0, stream>>>(mask, anym);
  zero_f32<<<1040, 256, 0, stream>>>(vkw, 64 * 65 * 64);

  // 4) in-place rmsnorm + rope + relu + mask on q/k slabs
  qkv_post<<<NBATCH * (L_SEQ + C_SEQ), 256, 0, stream>>>(
      qfs, kfs, mask, spos, anym, g_q, g_k, cg_q, cg_k);

  // 5) vk = vpad^T kf
  vk_accum<<<256, 256, 0, stream>>>(kfs, vfs, vkw);

  // 6) res = qf vk^T, divide, scatter to token-major (B,S,D)
  res_attn<<<576, 256, 0, stream>>>(qfs, vkw, attn_x, attn_c);

  // 7) output projections
  gemm_bias<bf16, false><<<dim3(8, 64), 256, 0, stream>>>(
      attn_x, WoutT, bout, y_x, nullptr, nullptr, nullptr, 8192, 1024, 1024, 0, 0);
  gemm_bias<bf16, false><<<dim3(8, 8), 256, 0, stream>>>(
      attn_c, cWoutT, cbout, y_c, nullptr, nullptr, nullptr, 1024, 1024, 1024, 0, 0);

  // 8) final rmsnorm -> FLOAT32 d_out (x_out rows then c_out rows)
  final_norm<<<NBATCH * (L_SEQ + C_SEQ), 256, 0, stream>>>(
      y_x, y_c, g_out, cg_out, (float*)d_out);
}